// Round 2
// baseline (676.029 us; speedup 1.0000x reference)
//
#include <hip/hip_runtime.h>
#include <hip/hip_bf16.h>
#include <stdint.h>

// GPTQOFTLinear: y = (x @ R_blockdiag) @ W^T + b
// Refactored: W' = W with each 64-col block right-multiplied by Q_r^T; y = x @ W'^T + b.
// Pipeline: cayley (64 GJ solves) -> fold W'+cast bf16 -> cast x bf16 -> bf16 MFMA GEMM (f32 out).

typedef __bf16 bf16;
typedef __attribute__((ext_vector_type(8))) __bf16 bf16x8;
typedef __attribute__((ext_vector_type(4))) float f32x4;

__device__ __forceinline__ bf16 f2bf(float f) {
  unsigned u = __builtin_bit_cast(unsigned, f);
  u += 0x7fffu + ((u >> 16) & 1u);          // RNE
  unsigned short h = (unsigned short)(u >> 16);
  return __builtin_bit_cast(bf16, h);
}

// ---------------- Kernel 1: Cayley ----------------
// Solve (I - S) X = (I + S) per block r; X = Q_r^T, S = 0.5*(D - D^T).
// Gauss-Jordan without pivoting (I-S diag-dominant, sing.values >= 1).
#define LDW 130
__global__ __launch_bounds__(256) void cayley_kernel(const float* __restrict__ oft_r,
                                                     float* __restrict__ Qx) {
  __shared__ float aug[64 * LDW];
  __shared__ float rowk[128];
  __shared__ float fac[64];
  const int tid = threadIdx.x;
  const int r = blockIdx.x;
  const float* D = oft_r + (size_t)r * 64 * 64;

  for (int idx = tid; idx < 64 * 128; idx += 256) {
    int i = idx >> 7, j = idx & 127;
    int jc = j & 63;
    float s = 0.5f * (D[i * 64 + jc] - D[jc * 64 + i]);
    float dg = (i == jc) ? 1.0f : 0.0f;
    aug[i * LDW + j] = (j < 64) ? (dg - s) : (dg + s);
  }
  __syncthreads();
  for (int k = 0; k < 64; ++k) {
    float invp = 1.0f / aug[k * LDW + k];
    if (tid < 128) rowk[tid] = aug[k * LDW + tid];
    if (tid < 64) fac[tid] = aug[tid * LDW + k] * invp;
    __syncthreads();
    for (int idx = tid; idx < 64 * 128; idx += 256) {
      int i = idx >> 7, j = idx & 127;
      float rv = rowk[j];
      if (i == k) aug[i * LDW + j] = rv * invp;
      else        aug[i * LDW + j] -= fac[i] * rv;
    }
    __syncthreads();
  }
  // right half = X = Q^T ; store row-major X[c][k]
  for (int idx = tid; idx < 4096; idx += 256) {
    int c = idx >> 6, kk = idx & 63;
    Qx[(size_t)r * 4096 + idx] = aug[c * LDW + 64 + kk];
  }
}

// ---------------- Kernel 2: fold rotation into W, cast bf16 ----------------
// Wp[o, r*64+k] = sum_c W[o, r*64+c] * X_r[c][k]
__global__ __launch_bounds__(256) void fold_w_kernel(const float* __restrict__ W,
                                                     const float* __restrict__ Qx,
                                                     bf16* __restrict__ Wp) {
  __shared__ float Wb[64 * 64];       // W block: [ol][c]
  __shared__ float XbT[64 * 65];      // X transposed: XbT[k][c] = X[c][k], pad 65
  const int tid = threadIdx.x;
  const int o0 = blockIdx.x * 64;
  const int r = blockIdx.y;

  for (int i = 0; i < 16; ++i) {
    int idx = tid + i * 256;          // 0..4095
    int c = idx >> 6, k = idx & 63;
    Wb[idx] = W[(size_t)(o0 + c) * 4096 + r * 64 + k]; // Wb[row=c][col=k] layout: idx = row*64+col
    XbT[k * 65 + c] = Qx[(size_t)r * 4096 + idx];      // coalesced read, transposed write
  }
  __syncthreads();

  const int kcol = tid & 63;
  const int rgroup = tid >> 6;        // wave id
  float xr[64];
#pragma unroll
  for (int c = 0; c < 64; ++c) xr[c] = XbT[kcol * 65 + c];  // X[c][kcol]

  for (int ii = 0; ii < 16; ++ii) {
    int ol = rgroup * 16 + ii;        // wave-uniform -> Wb reads broadcast
    float s = 0.f;
#pragma unroll
    for (int c = 0; c < 64; ++c) s += Wb[ol * 64 + c] * xr[c];
    Wp[(size_t)(o0 + ol) * 4096 + r * 64 + kcol] = f2bf(s);
  }
}

// ---------------- Kernel 3: cast x to bf16 ----------------
__global__ __launch_bounds__(256) void cast_x_kernel(const float* __restrict__ x,
                                                     bf16* __restrict__ xb, long n) {
  long i0 = ((long)blockIdx.x * 256 + threadIdx.x) * 8;
  long stride = (long)gridDim.x * 256 * 8;
  for (long i = i0; i < n; i += stride) {
    f32x4 a = *reinterpret_cast<const f32x4*>(x + i);
    f32x4 b = *reinterpret_cast<const f32x4*>(x + i + 4);
    bf16x8 o;
    o[0] = f2bf(a[0]); o[1] = f2bf(a[1]); o[2] = f2bf(a[2]); o[3] = f2bf(a[3]);
    o[4] = f2bf(b[0]); o[5] = f2bf(b[1]); o[6] = f2bf(b[2]); o[7] = f2bf(b[3]);
    *reinterpret_cast<bf16x8*>(xb + i) = o;
  }
}

// ---------------- Kernel 4: GEMM y = xb @ Wp^T + b (m97 structure) ----------------
// A [M,K] row-major bf16, B [N,K] row-major bf16 (B^T layout), C [M,N] f32.
constexpr int BM = 128, BN = 128, BK = 64;

#define GLDS16(g, l) __builtin_amdgcn_global_load_lds( \
    (const __attribute__((address_space(1))) unsigned int*)(g), \
    (__attribute__((address_space(3))) unsigned int*)(l), 16, 0, 0)

__global__ __launch_bounds__(256) void gemm_kernel(const bf16* __restrict__ A,
                                                   const bf16* __restrict__ B,
                                                   const float* __restrict__ bias,
                                                   float* __restrict__ C,
                                                   int M, int N, int K) {
  __shared__ bf16 As[BM * BK];   // [row][k] row-major, 16 KiB
  __shared__ bf16 Bs[BN * BK];

  const int tid = threadIdx.x;
  const int lane = tid & 63;
  const int wave = tid >> 6;
  const int wm = (wave >> 1) * 64;      // 2x2 wave grid, 64x64 per wave
  const int wn = (wave & 1) * 64;
  const int m0 = blockIdx.y * BM;
  const int n0 = blockIdx.x * BN;
  const int fr = lane & 15;             // fragment row/col
  const int kg = lane >> 4;             // k-group (8 elems each)

  f32x4 acc[4][4];
#pragma unroll
  for (int mi = 0; mi < 4; ++mi)
#pragma unroll
    for (int ni = 0; ni < 4; ++ni) acc[mi][ni] = (f32x4){0.f, 0.f, 0.f, 0.f};

  for (int k0 = 0; k0 < K; k0 += BK) {
    // stage A and B tiles: each tile = 128 rows x 64 bf16 = 128 rows x 8 chunks(16B)
    // chunk c (0..1023): row = c>>3, k-slice = (c&7)*8. LDS linear at c*8 elems.
#pragma unroll
    for (int i = 0; i < 4; ++i) {
      int c = i * 256 + tid;            // 16B chunk index, 1024 chunks/tile
      int row = c >> 3, kc = c & 7;
      const bf16* gA = A + (size_t)(m0 + row) * K + k0 + kc * 8;
      const bf16* gB = B + (size_t)(n0 + row) * K + k0 + kc * 8;
      int ldsbase = (i * 256 + wave * 64) * 8;   // wave-uniform; HW adds lane*16B
      GLDS16(gA, &As[ldsbase]);
      GLDS16(gB, &Bs[ldsbase]);
    }
    __syncthreads();                    // drains vmcnt+lgkm

#pragma unroll
    for (int kk = 0; kk < BK; kk += 32) {
      bf16x8 af[4], bf_[4];
#pragma unroll
      for (int mi = 0; mi < 4; ++mi)
        af[mi] = *reinterpret_cast<const bf16x8*>(&As[(wm + mi * 16 + fr) * BK + kk + kg * 8]);
#pragma unroll
      for (int ni = 0; ni < 4; ++ni)
        bf_[ni] = *reinterpret_cast<const bf16x8*>(&Bs[(wn + ni * 16 + fr) * BK + kk + kg * 8]);
#pragma unroll
      for (int mi = 0; mi < 4; ++mi)
#pragma unroll
        for (int ni = 0; ni < 4; ++ni)
          acc[mi][ni] = __builtin_amdgcn_mfma_f32_16x16x32_bf16(af[mi], bf_[ni], acc[mi][ni], 0, 0, 0);
    }
    __syncthreads();
  }

  // epilogue: D row = (lane>>4)*4 + reg, col = lane&15  [verified C/D layout]
#pragma unroll
  for (int ni = 0; ni < 4; ++ni) {
    int col = n0 + wn + ni * 16 + fr;
    float bv = bias[col];
#pragma unroll
    for (int mi = 0; mi < 4; ++mi) {
      int row0 = m0 + wm + mi * 16 + kg * 4;
#pragma unroll
      for (int q = 0; q < 4; ++q)
        C[(size_t)(row0 + q) * N + col] = acc[mi][ni][q] + bv;
    }
  }
}

extern "C" void kernel_launch(void* const* d_in, const int* in_sizes, int n_in,
                              void* d_out, int out_size, void* d_ws, size_t ws_size,
                              hipStream_t stream) {
  const float* x     = (const float*)d_in[0];   // [2,4096,4096]
  const float* oft_r = (const float*)d_in[1];   // [64,64,64]
  const float* W     = (const float*)d_in[2];   // [4096,4096]
  const float* b     = (const float*)d_in[3];   // [4096]
  float* y = (float*)d_out;                     // [8192,4096] f32

  // workspace layout (needs ~97 MiB)
  char* ws = (char*)d_ws;
  float* Qx = (float*)ws;                                  // 1 MiB: X = Q^T per block
  bf16*  Wp = (bf16*)(ws + (1u << 20));                    // 32 MiB: folded W, bf16
  bf16*  xb = (bf16*)(ws + (1u << 20) + (32u << 20));      // 64 MiB: x, bf16

  cayley_kernel<<<64, 256, 0, stream>>>(oft_r, Qx);
  dim3 fg(64, 64);                       // (o-chunks, rank)
  fold_w_kernel<<<fg, 256, 0, stream>>>(W, Qx, Wp);
  cast_x_kernel<<<2048, 256, 0, stream>>>(x, xb, 33554432L);
  dim3 gg(4096 / BN, 8192 / BM);         // (32, 64)
  gemm_kernel<<<gg, 256, 0, stream>>>(xb, Wp, b, y, 8192, 4096, 4096);
}

// Round 3
// 666.629 us; speedup vs baseline: 1.0141x; 1.0141x over previous
//
#include <hip/hip_runtime.h>
#include <hip/hip_bf16.h>
#include <stdint.h>

// GPTQOFTLinear: y = (x @ R_blockdiag) @ W^T + b
// Refactored: W' = W with each 64-col block right-multiplied by Q_r^T; y = x @ W'^T + b.
// Pipeline: cayley (64 GJ solves, stores X^T) -> fold W' via MFMA -> cast x bf16 -> bf16 MFMA GEMM.

typedef __bf16 bf16;
typedef __attribute__((ext_vector_type(4))) __bf16 bf16x4;
typedef __attribute__((ext_vector_type(8))) __bf16 bf16x8;
typedef __attribute__((ext_vector_type(4))) float f32x4;

__device__ __forceinline__ bf16 f2bf(float f) {
  unsigned u = __builtin_bit_cast(unsigned, f);
  u += 0x7fffu + ((u >> 16) & 1u);          // RNE
  unsigned short h = (unsigned short)(u >> 16);
  return __builtin_bit_cast(bf16, h);
}

// ---------------- Kernel 1: Cayley ----------------
// Solve (I - S) X = (I + S) per block r; X = Q_r^T, S = 0.5*(D - D^T).
// Gauss-Jordan without pivoting (I-S diag-dominant, sing.values >= 1).
// Output: Qxt[r][k][c] = X[c][k]  (transposed, feeds MFMA B-operand of fold)
#define LDW 130
__global__ __launch_bounds__(256) void cayley_kernel(const float* __restrict__ oft_r,
                                                     float* __restrict__ Qxt) {
  __shared__ float aug[64 * LDW];
  __shared__ float rowk[128];
  __shared__ float fac[64];
  const int tid = threadIdx.x;
  const int r = blockIdx.x;
  const float* D = oft_r + (size_t)r * 64 * 64;

  for (int idx = tid; idx < 64 * 128; idx += 256) {
    int i = idx >> 7, j = idx & 127;
    int jc = j & 63;
    float s = 0.5f * (D[i * 64 + jc] - D[jc * 64 + i]);
    float dg = (i == jc) ? 1.0f : 0.0f;
    aug[i * LDW + j] = (j < 64) ? (dg - s) : (dg + s);
  }
  __syncthreads();
  for (int k = 0; k < 64; ++k) {
    float invp = 1.0f / aug[k * LDW + k];
    if (tid < 128) rowk[tid] = aug[k * LDW + tid];
    if (tid < 64) fac[tid] = aug[tid * LDW + k] * invp;
    __syncthreads();
    for (int idx = tid; idx < 64 * 128; idx += 256) {
      int i = idx >> 7, j = idx & 127;
      float rv = rowk[j];
      if (i == k) aug[i * LDW + j] = rv * invp;
      else        aug[i * LDW + j] -= fac[i] * rv;
    }
    __syncthreads();
  }
  // right half = X (64x64, X[c][k] at aug[c][64+k]); store TRANSPOSED: Qxt[k][c] = X[c][k]
  for (int idx = tid; idx < 4096; idx += 256) {
    int k = idx >> 6, c = idx & 63;
    Qxt[(size_t)r * 4096 + idx] = aug[c * LDW + 64 + k];
  }
}

// ---------------- Kernel 2: fold rotation into W via MFMA ----------------
// Wp[o0+o, r*64+k] = sum_c W[o0+o, r*64+c] * X_r[c][k],  o in [0,128), k in [0,64)
// A = W block (128x64, cast bf16), B = Xt (64 rows=k, 64 cols=c, cast bf16), K=64.
__global__ __launch_bounds__(256) void fold_w_kernel(const float* __restrict__ W,
                                                     const float* __restrict__ Qxt,
                                                     bf16* __restrict__ Wp) {
  __shared__ bf16 Wb[128 * 64];   // [o][c] row-major, 16 KiB
  __shared__ bf16 Xt[64 * 64];    // [k][c] row-major, 8 KiB
  const int tid = threadIdx.x;
  const int lane = tid & 63;
  const int wave = tid >> 6;
  const int o0 = blockIdx.x * 128;
  const int r = blockIdx.y;
  const int fr = lane & 15;
  const int kg = lane >> 4;

  // stage W block: 128 rows x 16 f32x4 chunks = 2048 chunks, 8 per thread
#pragma unroll
  for (int i = 0; i < 8; ++i) {
    int c = i * 256 + tid;
    int row = c >> 4, c4 = c & 15;
    f32x4 v = *reinterpret_cast<const f32x4*>(W + (size_t)(o0 + row) * 4096 + r * 64 + c4 * 4);
    bf16x4 o; o[0] = f2bf(v[0]); o[1] = f2bf(v[1]); o[2] = f2bf(v[2]); o[3] = f2bf(v[3]);
    *reinterpret_cast<bf16x4*>(&Wb[row * 64 + c4 * 4]) = o;
  }
  // stage Xt: 64 rows x 16 chunks = 1024 chunks, 4 per thread
#pragma unroll
  for (int i = 0; i < 4; ++i) {
    int c = i * 256 + tid;
    int row = c >> 4, c4 = c & 15;
    f32x4 v = *reinterpret_cast<const f32x4*>(Qxt + (size_t)r * 4096 + row * 64 + c4 * 4);
    bf16x4 o; o[0] = f2bf(v[0]); o[1] = f2bf(v[1]); o[2] = f2bf(v[2]); o[3] = f2bf(v[3]);
    *reinterpret_cast<bf16x4*>(&Xt[row * 64 + c4 * 4]) = o;
  }
  __syncthreads();

  const int wm = wave * 32;             // each wave: 32 o-rows x 64 k-cols
  f32x4 acc[2][4];
#pragma unroll
  for (int mi = 0; mi < 2; ++mi)
#pragma unroll
    for (int ni = 0; ni < 4; ++ni) acc[mi][ni] = (f32x4){0.f, 0.f, 0.f, 0.f};

#pragma unroll
  for (int kk = 0; kk < 64; kk += 32) {
    bf16x8 af[2], bx[4];
#pragma unroll
    for (int mi = 0; mi < 2; ++mi)
      af[mi] = *reinterpret_cast<const bf16x8*>(&Wb[(wm + mi * 16 + fr) * 64 + kk + kg * 8]);
#pragma unroll
    for (int ni = 0; ni < 4; ++ni)
      bx[ni] = *reinterpret_cast<const bf16x8*>(&Xt[(ni * 16 + fr) * 64 + kk + kg * 8]);
#pragma unroll
    for (int mi = 0; mi < 2; ++mi)
#pragma unroll
      for (int ni = 0; ni < 4; ++ni)
        acc[mi][ni] = __builtin_amdgcn_mfma_f32_16x16x32_bf16(af[mi], bx[ni], acc[mi][ni], 0, 0, 0);
  }

  // D: row = kg*4 + q (+ mi*16 + wm), col = fr (+ ni*16)
#pragma unroll
  for (int mi = 0; mi < 2; ++mi)
#pragma unroll
    for (int ni = 0; ni < 4; ++ni)
#pragma unroll
      for (int q = 0; q < 4; ++q) {
        int row = o0 + wm + mi * 16 + kg * 4 + q;
        int col = ni * 16 + fr;
        Wp[(size_t)row * 4096 + r * 64 + col] = f2bf(acc[mi][ni][q]);
      }
}

// ---------------- Kernel 3: cast x to bf16 ----------------
__global__ __launch_bounds__(256) void cast_x_kernel(const float* __restrict__ x,
                                                     bf16* __restrict__ xb, long n) {
  long i0 = ((long)blockIdx.x * 256 + threadIdx.x) * 8;
  long stride = (long)gridDim.x * 256 * 8;
  for (long i = i0; i < n; i += stride) {
    f32x4 a = *reinterpret_cast<const f32x4*>(x + i);
    f32x4 b = *reinterpret_cast<const f32x4*>(x + i + 4);
    bf16x8 o;
    o[0] = f2bf(a[0]); o[1] = f2bf(a[1]); o[2] = f2bf(a[2]); o[3] = f2bf(a[3]);
    o[4] = f2bf(b[0]); o[5] = f2bf(b[1]); o[6] = f2bf(b[2]); o[7] = f2bf(b[3]);
    *reinterpret_cast<bf16x8*>(xb + i) = o;
  }
}

// ---------------- Kernel 4: GEMM y = xb @ Wp^T + b (m97 structure + T1 swizzle) ----
// A [M,K] row-major bf16, B [N,K] row-major bf16 (B^T layout), C [M,N] f32.
constexpr int BM = 128, BN = 128, BK = 64;

#define GLDS16(g, l) __builtin_amdgcn_global_load_lds( \
    (const __attribute__((address_space(1))) unsigned int*)(g), \
    (__attribute__((address_space(3))) unsigned int*)(l), 16, 0, 0)

__global__ __launch_bounds__(256) void gemm_kernel(const bf16* __restrict__ A,
                                                   const bf16* __restrict__ B,
                                                   const float* __restrict__ bias,
                                                   float* __restrict__ C,
                                                   int M, int N, int K) {
  __shared__ bf16 As[BM * BK];   // [row][k] row-major, 16 KiB
  __shared__ bf16 Bs[BN * BK];

  const int tid = threadIdx.x;
  const int lane = tid & 63;
  const int wave = tid >> 6;
  const int wm = (wave >> 1) * 64;      // 2x2 wave grid, 64x64 per wave
  const int wn = (wave & 1) * 64;

  // T1: XCD-aware swizzle (nwg = 2048, %8 == 0 -> simple bijective form)
  const int gx = gridDim.x;
  int bid = blockIdx.y * gx + blockIdx.x;
  int cpx = (gx * gridDim.y) >> 3;
  int swz = (bid & 7) * cpx + (bid >> 3);
  const int m0 = (swz / gx) * BM;
  const int n0 = (swz % gx) * BN;

  const int fr = lane & 15;             // fragment row/col
  const int kg = lane >> 4;             // k-group (8 elems each)

  f32x4 acc[4][4];
#pragma unroll
  for (int mi = 0; mi < 4; ++mi)
#pragma unroll
    for (int ni = 0; ni < 4; ++ni) acc[mi][ni] = (f32x4){0.f, 0.f, 0.f, 0.f};

  for (int k0 = 0; k0 < K; k0 += BK) {
    // stage A and B tiles: each tile = 128 rows x 8 chunks(16B); chunk c: row=c>>3, k=(c&7)*8
#pragma unroll
    for (int i = 0; i < 4; ++i) {
      int c = i * 256 + tid;
      int row = c >> 3, kc = c & 7;
      const bf16* gA = A + (size_t)(m0 + row) * K + k0 + kc * 8;
      const bf16* gB = B + (size_t)(n0 + row) * K + k0 + kc * 8;
      int ldsbase = (i * 256 + wave * 64) * 8;   // wave-uniform; HW adds lane*16B
      GLDS16(gA, &As[ldsbase]);
      GLDS16(gB, &Bs[ldsbase]);
    }
    __syncthreads();

#pragma unroll
    for (int kk = 0; kk < BK; kk += 32) {
      bf16x8 af[4], bf_[4];
#pragma unroll
      for (int mi = 0; mi < 4; ++mi)
        af[mi] = *reinterpret_cast<const bf16x8*>(&As[(wm + mi * 16 + fr) * BK + kk + kg * 8]);
#pragma unroll
      for (int ni = 0; ni < 4; ++ni)
        bf_[ni] = *reinterpret_cast<const bf16x8*>(&Bs[(wn + ni * 16 + fr) * BK + kk + kg * 8]);
#pragma unroll
      for (int mi = 0; mi < 4; ++mi)
#pragma unroll
        for (int ni = 0; ni < 4; ++ni)
          acc[mi][ni] = __builtin_amdgcn_mfma_f32_16x16x32_bf16(af[mi], bf_[ni], acc[mi][ni], 0, 0, 0);
    }
    __syncthreads();
  }

  // epilogue: D row = (lane>>4)*4 + reg, col = lane&15
#pragma unroll
  for (int ni = 0; ni < 4; ++ni) {
    int col = n0 + wn + ni * 16 + fr;
    float bv = bias[col];
#pragma unroll
    for (int mi = 0; mi < 4; ++mi) {
      int row0 = m0 + wm + mi * 16 + kg * 4;
#pragma unroll
      for (int q = 0; q < 4; ++q)
        C[(size_t)(row0 + q) * N + col] = acc[mi][ni][q] + bv;
    }
  }
}

extern "C" void kernel_launch(void* const* d_in, const int* in_sizes, int n_in,
                              void* d_out, int out_size, void* d_ws, size_t ws_size,
                              hipStream_t stream) {
  const float* x     = (const float*)d_in[0];   // [2,4096,4096]
  const float* oft_r = (const float*)d_in[1];   // [64,64,64]
  const float* W     = (const float*)d_in[2];   // [4096,4096]
  const float* b     = (const float*)d_in[3];   // [4096]
  float* y = (float*)d_out;                     // [8192,4096] f32

  // workspace layout (~97 MiB)
  char* ws = (char*)d_ws;
  float* Qxt = (float*)ws;                                 // 1 MiB: X^T per block
  bf16*  Wp  = (bf16*)(ws + (1u << 20));                   // 32 MiB: folded W, bf16
  bf16*  xb  = (bf16*)(ws + (1u << 20) + (32u << 20));     // 64 MiB: x, bf16

  cayley_kernel<<<64, 256, 0, stream>>>(oft_r, Qxt);
  dim3 fg(32, 64);                       // (o-chunks of 128, rank)
  fold_w_kernel<<<fg, 256, 0, stream>>>(W, Qxt, Wp);
  cast_x_kernel<<<2048, 256, 0, stream>>>(x, xb, 33554432L);
  dim3 gg(4096 / BN, 8192 / BM);         // (32, 64)
  gemm_kernel<<<gg, 256, 0, stream>>>(xb, Wp, b, y, 8192, 4096, 4096);
}

// Round 4
// 365.000 us; speedup vs baseline: 1.8521x; 1.8264x over previous
//
#include <hip/hip_runtime.h>
#include <hip/hip_bf16.h>
#include <stdint.h>

// GPTQOFTLinear: y = (x @ R_blockdiag) @ W^T + b
// W' = W with each 64-col block right-multiplied by Q_r^T; y = x @ W'^T + b.
// cayley (Neumann series) -> fold W' via MFMA -> cast x bf16 -> 256^2 8-phase bf16 GEMM.

typedef __bf16 bf16;
typedef __attribute__((ext_vector_type(4))) __bf16 bf16x4;
typedef __attribute__((ext_vector_type(8))) __bf16 bf16x8;
typedef __attribute__((ext_vector_type(4))) float f32x4;

__device__ __forceinline__ bf16 f2bf(float f) {
  unsigned u = __builtin_bit_cast(unsigned, f);
  u += 0x7fffu + ((u >> 16) & 1u);          // RNE
  unsigned short h = (unsigned short)(u >> 16);
  return __builtin_bit_cast(bf16, h);
}

// ---------------- Kernel 1: Cayley via Neumann series ----------------
// S = 0.5(D - D^T), ||S|| ~ 0.23.  T5 = order-6 series for (I+S)^{-1}; Q = (I-S)T5.
// Output Q row-major: Qxt[r][i][j] = Q[i][j]  (== X[j][i], what fold consumes as B^T).
__global__ __launch_bounds__(256) void cayley_kernel(const float* __restrict__ oft_r,
                                                     float* __restrict__ Qxt) {
  __shared__ float S[64][65];
  __shared__ float Ta[64][65];
  __shared__ float Tb[64][65];
  const int tid = threadIdx.x;
  const int r = blockIdx.x;
  const float* D = oft_r + (size_t)r * 4096;

  for (int idx = tid; idx < 4096; idx += 256) {
    int i = idx >> 6, j = idx & 63;
    float s = 0.5f * (D[i * 64 + j] - D[j * 64 + i]);
    S[i][j] = s;
    Ta[i][j] = (i == j ? 1.0f : 0.0f) - s;   // T0 = I - S (order 1)
  }
  __syncthreads();

  const int j = tid & 63;
  const int w = tid >> 6;
  float (*Tin)[65] = Ta;
  float (*Tout)[65] = Tb;

  for (int it = 0; it < 5; ++it) {           // each iter adds one order: final = order 6
    float tcol[64];
#pragma unroll
    for (int c = 0; c < 64; ++c) tcol[c] = Tin[c][j];
    float out[16];
    for (int m = 0; m < 16; ++m) {
      int i = w * 16 + m;
      float s = 0.f;
#pragma unroll
      for (int c = 0; c < 64; ++c) s += S[i][c] * tcol[c];   // S read = wave-uniform broadcast
      out[m] = (i == j ? 1.0f : 0.0f) - s;   // T_new = I - S*T
    }
    for (int m = 0; m < 16; ++m) Tout[w * 16 + m][j] = out[m];
    __syncthreads();
    float (*tmp)[65] = Tin; Tin = Tout; Tout = tmp;
  }
  // Q = (I - S) * T
  {
    float tcol[64];
#pragma unroll
    for (int c = 0; c < 64; ++c) tcol[c] = Tin[c][j];
    for (int m = 0; m < 16; ++m) {
      int i = w * 16 + m;
      float s = 0.f;
#pragma unroll
      for (int c = 0; c < 64; ++c) s += S[i][c] * tcol[c];
      Qxt[(size_t)r * 4096 + i * 64 + j] = Tin[i][j] - s;
    }
  }
}

// ---------------- Kernel 2: fold rotation into W via MFMA ----------------
// Wp[o, r*64+k] = sum_c W[o, r*64+c] * Q[k][c]   (Qxt = Q row-major, consumed B^T-style)
__global__ __launch_bounds__(256) void fold_w_kernel(const float* __restrict__ W,
                                                     const float* __restrict__ Qxt,
                                                     bf16* __restrict__ Wp) {
  __shared__ bf16 Wb[128 * 64];
  __shared__ bf16 Xt[64 * 64];
  const int tid = threadIdx.x;
  const int lane = tid & 63;
  const int wave = tid >> 6;
  const int o0 = blockIdx.x * 128;
  const int r = blockIdx.y;
  const int fr = lane & 15;
  const int kg = lane >> 4;

#pragma unroll
  for (int i = 0; i < 8; ++i) {
    int c = i * 256 + tid;
    int row = c >> 4, c4 = c & 15;
    f32x4 v = *reinterpret_cast<const f32x4*>(W + (size_t)(o0 + row) * 4096 + r * 64 + c4 * 4);
    bf16x4 o; o[0] = f2bf(v[0]); o[1] = f2bf(v[1]); o[2] = f2bf(v[2]); o[3] = f2bf(v[3]);
    *reinterpret_cast<bf16x4*>(&Wb[row * 64 + c4 * 4]) = o;
  }
#pragma unroll
  for (int i = 0; i < 4; ++i) {
    int c = i * 256 + tid;
    int row = c >> 4, c4 = c & 15;
    f32x4 v = *reinterpret_cast<const f32x4*>(Qxt + (size_t)r * 4096 + row * 64 + c4 * 4);
    bf16x4 o; o[0] = f2bf(v[0]); o[1] = f2bf(v[1]); o[2] = f2bf(v[2]); o[3] = f2bf(v[3]);
    *reinterpret_cast<bf16x4*>(&Xt[row * 64 + c4 * 4]) = o;
  }
  __syncthreads();

  const int wm = wave * 32;
  f32x4 acc[2][4];
#pragma unroll
  for (int mi = 0; mi < 2; ++mi)
#pragma unroll
    for (int ni = 0; ni < 4; ++ni) acc[mi][ni] = (f32x4){0.f, 0.f, 0.f, 0.f};

#pragma unroll
  for (int kk = 0; kk < 64; kk += 32) {
    bf16x8 af[2], bx[4];
#pragma unroll
    for (int mi = 0; mi < 2; ++mi)
      af[mi] = *reinterpret_cast<const bf16x8*>(&Wb[(wm + mi * 16 + fr) * 64 + kk + kg * 8]);
#pragma unroll
    for (int ni = 0; ni < 4; ++ni)
      bx[ni] = *reinterpret_cast<const bf16x8*>(&Xt[(ni * 16 + fr) * 64 + kk + kg * 8]);
#pragma unroll
    for (int mi = 0; mi < 2; ++mi)
#pragma unroll
      for (int ni = 0; ni < 4; ++ni)
        acc[mi][ni] = __builtin_amdgcn_mfma_f32_16x16x32_bf16(af[mi], bx[ni], acc[mi][ni], 0, 0, 0);
  }

#pragma unroll
  for (int mi = 0; mi < 2; ++mi)
#pragma unroll
    for (int ni = 0; ni < 4; ++ni)
#pragma unroll
      for (int q = 0; q < 4; ++q) {
        int row = o0 + wm + mi * 16 + kg * 4 + q;
        int col = ni * 16 + fr;
        Wp[(size_t)row * 4096 + r * 64 + col] = f2bf(acc[mi][ni][q]);
      }
}

// ---------------- Kernel 3: cast x to bf16 ----------------
__global__ __launch_bounds__(256) void cast_x_kernel(const float* __restrict__ x,
                                                     bf16* __restrict__ xb, long n) {
  long i0 = ((long)blockIdx.x * 256 + threadIdx.x) * 8;
  long stride = (long)gridDim.x * 256 * 8;
  for (long i = i0; i < n; i += stride) {
    f32x4 a = *reinterpret_cast<const f32x4*>(x + i);
    f32x4 b = *reinterpret_cast<const f32x4*>(x + i + 4);
    bf16x8 o;
    o[0] = f2bf(a[0]); o[1] = f2bf(a[1]); o[2] = f2bf(a[2]); o[3] = f2bf(a[3]);
    o[4] = f2bf(b[0]); o[5] = f2bf(b[1]); o[6] = f2bf(b[2]); o[7] = f2bf(b[3]);
    *reinterpret_cast<bf16x8*>(xb + i) = o;
  }
}

// ---------------- Kernel 4: 256x256 8-phase GEMM, y = xb @ Wp^T + b ----------------
// A [M,K] bf16 row-major, B [N,K] bf16 row-major (B^T layout), C [M,N] f32.
// 512 thr = 8 waves (2M x 4N), BK=64 split in two K-halves, double-buffered 128 KiB LDS.
// LDS elem layout: [buf(2)][op(A,B)][ks(2)][row(256)][chunk(4)*8], chunk XOR-swizzled by row&3.
// Staging: global_load_lds 16B, linear LDS dest, inverse-swizzled global src (rule #21).
// Waits: vmcnt(4) at P1/P3 only (4 newest = next tile's 2 pairs stay in flight); raw s_barrier.

#define GLDS16(g, l) __builtin_amdgcn_global_load_lds( \
    (const __attribute__((address_space(1))) unsigned int*)(g), \
    (__attribute__((address_space(3))) unsigned int*)(l), 16, 0, 0)

#define VMCNT4 asm volatile("s_waitcnt vmcnt(4)" ::: "memory")
#define VMCNT0 asm volatile("s_waitcnt vmcnt(0)" ::: "memory")
#define BARRIER() do { asm volatile("" ::: "memory"); \
  __builtin_amdgcn_s_barrier(); asm volatile("" ::: "memory"); } while (0)

__global__ __launch_bounds__(512, 2) void gemm_kernel(const bf16* __restrict__ A,
                                                      const bf16* __restrict__ B,
                                                      const float* __restrict__ bias,
                                                      float* __restrict__ C,
                                                      int M, int N, int K) {
  __shared__ bf16 lds[65536];   // 128 KiB
  const int tid = threadIdx.x;
  const int lane = tid & 63;
  const int wave = tid >> 6;
  const int wr = wave >> 2;          // 0..1  (M)
  const int wc = wave & 3;           // 0..3  (N)
  const int fr = lane & 15;
  const int kg = lane >> 4;
  const int m0 = blockIdx.y * 256;
  const int n0 = blockIdx.x * 256;
  const int NT = K >> 6;

  f32x4 acc[8][4];
#pragma unroll
  for (int m = 0; m < 8; ++m)
#pragma unroll
    for (int n = 0; n < 4; ++n) acc[m][n] = (f32x4){0.f, 0.f, 0.f, 0.f};

  // stage pair p (0:A-k0 1:B-k0 2:A-k1 3:B-k1) of K-tile t into buffer t&1
  auto STAGE = [&](int t, int p) {
    const int op = p & 1, ks = p >> 1;
    const bf16* src = op ? B : A;
    const int base_row = op ? n0 : m0;
    const int ldsb = (t & 1) * 32768 + op * 16384 + ks * 8192;
#pragma unroll
    for (int i = 0; i < 2; ++i) {
      int c = i * 512 + tid;           // 1024 chunks of 16B per half-tile
      int row = c >> 2, cc = c & 3;
      const bf16* g = src + (size_t)(base_row + row) * K + t * 64 + ks * 32
                      + ((cc ^ (row & 3)) << 3);          // inverse-swizzled source
      GLDS16(g, &lds[ldsb + ((i * 512 + wave * 64) << 3)]); // linear dest (+lane*16B by HW)
    }
  };
  auto LDA = [&](int buf, int ks, int mi) -> bf16x8 {
    int row = wr * 128 + mi * 16 + fr;
    return *reinterpret_cast<const bf16x8*>(
        &lds[buf * 32768 + ks * 8192 + row * 32 + ((kg ^ (fr & 3)) << 3)]);
  };
  auto LDB = [&](int buf, int ks, int ni) -> bf16x8 {
    int row = wc * 64 + ni * 16 + fr;
    return *reinterpret_cast<const bf16x8*>(
        &lds[buf * 32768 + 16384 + ks * 8192 + row * 32 + ((kg ^ (fr & 3)) << 3)]);
  };

  // prologue: stage tile 0 fully; wait for its k0 halves (k1 pair may fly)
#pragma unroll
  for (int p = 0; p < 4; ++p) STAGE(0, p);
  VMCNT4;
  BARRIER();

  bf16x8 afr[4], bfr[4];
  for (int t = 0; t < NT; ++t) {
    const int bc = t & 1;
    const bool pre = (t + 1 < NT);

    // ---- P0: ks=0, mi 0-3 ----
    if (pre) STAGE(t + 1, 0);
#pragma unroll
    for (int n = 0; n < 4; ++n) bfr[n] = LDB(bc, 0, n);
#pragma unroll
    for (int m = 0; m < 4; ++m) afr[m] = LDA(bc, 0, m);
    BARRIER();
    __builtin_amdgcn_s_setprio(1);
#pragma unroll
    for (int m = 0; m < 4; ++m)
#pragma unroll
      for (int n = 0; n < 4; ++n)
        acc[m][n] = __builtin_amdgcn_mfma_f32_16x16x32_bf16(afr[m], bfr[n], acc[m][n], 0, 0, 0);
    __builtin_amdgcn_s_setprio(0);

    // ---- P1: ks=0, mi 4-7 ----
    if (pre) STAGE(t + 1, 1);
#pragma unroll
    for (int m = 0; m < 4; ++m) afr[m] = LDA(bc, 0, 4 + m);
    if (pre) { VMCNT4; } else { VMCNT0; }   // publish this tile's k1 halves
    BARRIER();
    __builtin_amdgcn_s_setprio(1);
#pragma unroll
    for (int m = 0; m < 4; ++m)
#pragma unroll
      for (int n = 0; n < 4; ++n)
        acc[4 + m][n] = __builtin_amdgcn_mfma_f32_16x16x32_bf16(afr[m], bfr[n], acc[4 + m][n], 0, 0, 0);
    __builtin_amdgcn_s_setprio(0);

    // ---- P2: ks=1, mi 0-3 ----
    if (pre) STAGE(t + 1, 2);
#pragma unroll
    for (int n = 0; n < 4; ++n) bfr[n] = LDB(bc, 1, n);
#pragma unroll
    for (int m = 0; m < 4; ++m) afr[m] = LDA(bc, 1, m);
    BARRIER();
    __builtin_amdgcn_s_setprio(1);
#pragma unroll
    for (int m = 0; m < 4; ++m)
#pragma unroll
      for (int n = 0; n < 4; ++n)
        acc[m][n] = __builtin_amdgcn_mfma_f32_16x16x32_bf16(afr[m], bfr[n], acc[m][n], 0, 0, 0);
    __builtin_amdgcn_s_setprio(0);

    // ---- P3: ks=1, mi 4-7 ----
    if (pre) STAGE(t + 1, 3);
#pragma unroll
    for (int m = 0; m < 4; ++m) afr[m] = LDA(bc, 1, 4 + m);
    if (pre) { VMCNT4; } else { VMCNT0; }   // publish next tile's k0 halves
    BARRIER();
    __builtin_amdgcn_s_setprio(1);
#pragma unroll
    for (int m = 0; m < 4; ++m)
#pragma unroll
      for (int n = 0; n < 4; ++n)
        acc[4 + m][n] = __builtin_amdgcn_mfma_f32_16x16x32_bf16(afr[m], bfr[n], acc[4 + m][n], 0, 0, 0);
    __builtin_amdgcn_s_setprio(0);
  }

  // epilogue: D row = kg*4+q (+16*m blocks), col = fr (+16*n)
#pragma unroll
  for (int n = 0; n < 4; ++n) {
    int col = n0 + wc * 64 + n * 16 + fr;
    float bv = bias[col];
#pragma unroll
    for (int m = 0; m < 8; ++m) {
      int row0 = m0 + wr * 128 + m * 16 + kg * 4;
#pragma unroll
      for (int q = 0; q < 4; ++q)
        C[(size_t)(row0 + q) * N + col] = acc[m][n][q] + bv;
    }
  }
}

extern "C" void kernel_launch(void* const* d_in, const int* in_sizes, int n_in,
                              void* d_out, int out_size, void* d_ws, size_t ws_size,
                              hipStream_t stream) {
  const float* x     = (const float*)d_in[0];   // [2,4096,4096]
  const float* oft_r = (const float*)d_in[1];   // [64,64,64]
  const float* W     = (const float*)d_in[2];   // [4096,4096]
  const float* b     = (const float*)d_in[3];   // [4096]
  float* y = (float*)d_out;                     // [8192,4096] f32

  char* ws = (char*)d_ws;
  float* Qxt = (float*)ws;                                 // 1 MiB: Q row-major per block
  bf16*  Wp  = (bf16*)(ws + (1u << 20));                   // 32 MiB: folded W, bf16
  bf16*  xb  = (bf16*)(ws + (1u << 20) + (32u << 20));     // 64 MiB: x, bf16

  cayley_kernel<<<64, 256, 0, stream>>>(oft_r, Qxt);
  dim3 fg(32, 64);
  fold_w_kernel<<<fg, 256, 0, stream>>>(W, Qxt, Wp);
  cast_x_kernel<<<2048, 256, 0, stream>>>(x, xb, 33554432L);
  dim3 gg(4096 / 256, 8192 / 256);   // (16, 32)
  gemm_kernel<<<gg, 512, 0, stream>>>(xb, Wp, b, y, 8192, 4096, 4096);
}

// Round 5
// 364.011 us; speedup vs baseline: 1.8572x; 1.0027x over previous
//
#include <hip/hip_runtime.h>
#include <hip/hip_bf16.h>
#include <stdint.h>

// GPTQOFTLinear: y = (x @ R_blockdiag) @ W^T + b
// W' = W with each 64-col block right-multiplied by Q_r^T; y = x @ W'^T + b.
// cayley (Neumann series) -> fold W' via MFMA -> cast x bf16 -> 256^2 8-phase bf16 GEMM.

typedef __bf16 bf16;
typedef __attribute__((ext_vector_type(4))) __bf16 bf16x4;
typedef __attribute__((ext_vector_type(8))) __bf16 bf16x8;
typedef __attribute__((ext_vector_type(4))) float f32x4;

__device__ __forceinline__ bf16 f2bf(float f) {
  unsigned u = __builtin_bit_cast(unsigned, f);
  u += 0x7fffu + ((u >> 16) & 1u);          // RNE
  unsigned short h = (unsigned short)(u >> 16);
  return __builtin_bit_cast(bf16, h);
}

// ---------------- Kernel 1: Cayley via Neumann series ----------------
// S = 0.5(D - D^T), ||S|| ~ 0.23.  T5 = order-6 series for (I+S)^{-1}; Q = (I-S)T5.
// Output Q row-major: Qxt[r][i][j] = Q[i][j]  (== X[j][i], what fold consumes as B^T).
__global__ __launch_bounds__(256) void cayley_kernel(const float* __restrict__ oft_r,
                                                     float* __restrict__ Qxt) {
  __shared__ float S[64][65];
  __shared__ float Ta[64][65];
  __shared__ float Tb[64][65];
  const int tid = threadIdx.x;
  const int r = blockIdx.x;
  const float* D = oft_r + (size_t)r * 4096;

  for (int idx = tid; idx < 4096; idx += 256) {
    int i = idx >> 6, j = idx & 63;
    float s = 0.5f * (D[i * 64 + j] - D[j * 64 + i]);
    S[i][j] = s;
    Ta[i][j] = (i == j ? 1.0f : 0.0f) - s;   // T0 = I - S (order 1)
  }
  __syncthreads();

  const int j = tid & 63;
  const int w = tid >> 6;
  float (*Tin)[65] = Ta;
  float (*Tout)[65] = Tb;

  for (int it = 0; it < 5; ++it) {           // each iter adds one order: final = order 6
    float tcol[64];
#pragma unroll
    for (int c = 0; c < 64; ++c) tcol[c] = Tin[c][j];
    float out[16];
    for (int m = 0; m < 16; ++m) {
      int i = w * 16 + m;
      float s = 0.f;
#pragma unroll
      for (int c = 0; c < 64; ++c) s += S[i][c] * tcol[c];   // S read = wave-uniform broadcast
      out[m] = (i == j ? 1.0f : 0.0f) - s;   // T_new = I - S*T
    }
    for (int m = 0; m < 16; ++m) Tout[w * 16 + m][j] = out[m];
    __syncthreads();
    float (*tmp)[65] = Tin; Tin = Tout; Tout = tmp;
  }
  // Q = (I - S) * T
  {
    float tcol[64];
#pragma unroll
    for (int c = 0; c < 64; ++c) tcol[c] = Tin[c][j];
    for (int m = 0; m < 16; ++m) {
      int i = w * 16 + m;
      float s = 0.f;
#pragma unroll
      for (int c = 0; c < 64; ++c) s += S[i][c] * tcol[c];
      Qxt[(size_t)r * 4096 + i * 64 + j] = Tin[i][j] - s;
    }
  }
}

// ---------------- Kernel 2: fold rotation into W via MFMA ----------------
// Wp[o, r*64+k] = sum_c W[o, r*64+c] * Q[k][c]   (Qxt = Q row-major, consumed B^T-style)
__global__ __launch_bounds__(256) void fold_w_kernel(const float* __restrict__ W,
                                                     const float* __restrict__ Qxt,
                                                     bf16* __restrict__ Wp) {
  __shared__ bf16 Wb[128 * 64];
  __shared__ bf16 Xt[64 * 64];
  const int tid = threadIdx.x;
  const int lane = tid & 63;
  const int wave = tid >> 6;
  const int o0 = blockIdx.x * 128;
  const int r = blockIdx.y;
  const int fr = lane & 15;
  const int kg = lane >> 4;

#pragma unroll
  for (int i = 0; i < 8; ++i) {
    int c = i * 256 + tid;
    int row = c >> 4, c4 = c & 15;
    f32x4 v = *reinterpret_cast<const f32x4*>(W + (size_t)(o0 + row) * 4096 + r * 64 + c4 * 4);
    bf16x4 o; o[0] = f2bf(v[0]); o[1] = f2bf(v[1]); o[2] = f2bf(v[2]); o[3] = f2bf(v[3]);
    *reinterpret_cast<bf16x4*>(&Wb[row * 64 + c4 * 4]) = o;
  }
#pragma unroll
  for (int i = 0; i < 4; ++i) {
    int c = i * 256 + tid;
    int row = c >> 4, c4 = c & 15;
    f32x4 v = *reinterpret_cast<const f32x4*>(Qxt + (size_t)r * 4096 + row * 64 + c4 * 4);
    bf16x4 o; o[0] = f2bf(v[0]); o[1] = f2bf(v[1]); o[2] = f2bf(v[2]); o[3] = f2bf(v[3]);
    *reinterpret_cast<bf16x4*>(&Xt[row * 64 + c4 * 4]) = o;
  }
  __syncthreads();

  const int wm = wave * 32;
  f32x4 acc[2][4];
#pragma unroll
  for (int mi = 0; mi < 2; ++mi)
#pragma unroll
    for (int ni = 0; ni < 4; ++ni) acc[mi][ni] = (f32x4){0.f, 0.f, 0.f, 0.f};

#pragma unroll
  for (int kk = 0; kk < 64; kk += 32) {
    bf16x8 af[2], bx[4];
#pragma unroll
    for (int mi = 0; mi < 2; ++mi)
      af[mi] = *reinterpret_cast<const bf16x8*>(&Wb[(wm + mi * 16 + fr) * 64 + kk + kg * 8]);
#pragma unroll
    for (int ni = 0; ni < 4; ++ni)
      bx[ni] = *reinterpret_cast<const bf16x8*>(&Xt[(ni * 16 + fr) * 64 + kk + kg * 8]);
#pragma unroll
    for (int mi = 0; mi < 2; ++mi)
#pragma unroll
      for (int ni = 0; ni < 4; ++ni)
        acc[mi][ni] = __builtin_amdgcn_mfma_f32_16x16x32_bf16(af[mi], bx[ni], acc[mi][ni], 0, 0, 0);
  }

#pragma unroll
  for (int mi = 0; mi < 2; ++mi)
#pragma unroll
    for (int ni = 0; ni < 4; ++ni)
#pragma unroll
      for (int q = 0; q < 4; ++q) {
        int row = o0 + wm + mi * 16 + kg * 4 + q;
        int col = ni * 16 + fr;
        Wp[(size_t)row * 4096 + r * 64 + col] = f2bf(acc[mi][ni][q]);
      }
}

// ---------------- Kernel 3: cast x to bf16 ----------------
__global__ __launch_bounds__(256) void cast_x_kernel(const float* __restrict__ x,
                                                     bf16* __restrict__ xb, long n) {
  long i0 = ((long)blockIdx.x * 256 + threadIdx.x) * 8;
  long stride = (long)gridDim.x * 256 * 8;
  for (long i = i0; i < n; i += stride) {
    f32x4 a = *reinterpret_cast<const f32x4*>(x + i);
    f32x4 b = *reinterpret_cast<const f32x4*>(x + i + 4);
    bf16x8 o;
    o[0] = f2bf(a[0]); o[1] = f2bf(a[1]); o[2] = f2bf(a[2]); o[3] = f2bf(a[3]);
    o[4] = f2bf(b[0]); o[5] = f2bf(b[1]); o[6] = f2bf(b[2]); o[7] = f2bf(b[3]);
    *reinterpret_cast<bf16x8*>(xb + i) = o;
  }
}

// ---------------- Kernel 4: 256x256 8-phase GEMM, y = xb @ Wp^T + b ----------------
// A [M,K] bf16 row-major, B [N,K] bf16 row-major (B^T layout), C [M,N] f32.
// 512 thr = 8 waves (2M x 4N), BK=64 split in two K-halves, double-buffered 128 KiB LDS.
// LDS elem layout: [buf(2)][op(A,B)][ks(2)][row(256)][chunk(4)*8].
// Swizzle key = (row>>1)&3: quarter-wave lanes (rows base..base+15) hit each 4-bank slot
// exactly 2x (free, m136); key row&3 was constant across colliding rows (4-way, r4's 2.5e7).
// Staging: global_load_lds 16B, linear LDS dest, inverse-swizzled global src (rule #21).
// Waits: vmcnt(4) at P1/P3 only (4 newest = next tile's 2 pairs stay in flight); raw s_barrier.

#define GLDS16(g, l) __builtin_amdgcn_global_load_lds( \
    (const __attribute__((address_space(1))) unsigned int*)(g), \
    (__attribute__((address_space(3))) unsigned int*)(l), 16, 0, 0)

#define VMCNT4 asm volatile("s_waitcnt vmcnt(4)" ::: "memory")
#define VMCNT0 asm volatile("s_waitcnt vmcnt(0)" ::: "memory")
#define BARRIER() do { asm volatile("" ::: "memory"); \
  __builtin_amdgcn_s_barrier(); asm volatile("" ::: "memory"); } while (0)

__global__ __launch_bounds__(512, 2) void gemm_kernel(const bf16* __restrict__ A,
                                                      const bf16* __restrict__ B,
                                                      const float* __restrict__ bias,
                                                      float* __restrict__ C,
                                                      int M, int N, int K) {
  __shared__ bf16 lds[65536];   // 128 KiB
  const int tid = threadIdx.x;
  const int lane = tid & 63;
  const int wave = tid >> 6;
  const int wr = wave >> 2;          // 0..1  (M)
  const int wc = wave & 3;           // 0..3  (N)
  const int fr = lane & 15;
  const int kg = lane >> 4;
  const int m0 = blockIdx.y * 256;
  const int n0 = blockIdx.x * 256;
  const int NT = K >> 6;

  f32x4 acc[8][4];
#pragma unroll
  for (int m = 0; m < 8; ++m)
#pragma unroll
    for (int n = 0; n < 4; ++n) acc[m][n] = (f32x4){0.f, 0.f, 0.f, 0.f};

  // stage pair p (0:A-k0 1:B-k0 2:A-k1 3:B-k1) of K-tile t into buffer t&1
  auto STAGE = [&](int t, int p) {
    const int op = p & 1, ks = p >> 1;
    const bf16* src = op ? B : A;
    const int base_row = op ? n0 : m0;
    const int ldsb = (t & 1) * 32768 + op * 16384 + ks * 8192;
#pragma unroll
    for (int i = 0; i < 2; ++i) {
      int c = i * 512 + tid;           // 1024 chunks of 16B per half-tile
      int row = c >> 2, cc = c & 3;
      const bf16* g = src + (size_t)(base_row + row) * K + t * 64 + ks * 32
                      + ((cc ^ ((row >> 1) & 3)) << 3);      // inverse-swizzled source
      GLDS16(g, &lds[ldsb + ((i * 512 + wave * 64) << 3)]); // linear dest (+lane*16B by HW)
    }
  };
  auto LDA = [&](int buf, int ks, int mi) -> bf16x8 {
    int row = wr * 128 + mi * 16 + fr;
    return *reinterpret_cast<const bf16x8*>(
        &lds[buf * 32768 + ks * 8192 + row * 32 + ((kg ^ ((row >> 1) & 3)) << 3)]);
  };
  auto LDB = [&](int buf, int ks, int ni) -> bf16x8 {
    int row = wc * 64 + ni * 16 + fr;
    return *reinterpret_cast<const bf16x8*>(
        &lds[buf * 32768 + 16384 + ks * 8192 + row * 32 + ((kg ^ ((row >> 1) & 3)) << 3)]);
  };

  // prologue: stage tile 0 fully; wait for its k0 halves (k1 pair may fly)
#pragma unroll
  for (int p = 0; p < 4; ++p) STAGE(0, p);
  VMCNT4;
  BARRIER();

  bf16x8 afr[4], bfr[4];
  for (int t = 0; t < NT; ++t) {
    const int bc = t & 1;
    const bool pre = (t + 1 < NT);

    // ---- P0: ks=0, mi 0-3 ----
    if (pre) STAGE(t + 1, 0);
#pragma unroll
    for (int n = 0; n < 4; ++n) bfr[n] = LDB(bc, 0, n);
#pragma unroll
    for (int m = 0; m < 4; ++m) afr[m] = LDA(bc, 0, m);
    BARRIER();
    __builtin_amdgcn_s_setprio(1);
#pragma unroll
    for (int m = 0; m < 4; ++m)
#pragma unroll
      for (int n = 0; n < 4; ++n)
        acc[m][n] = __builtin_amdgcn_mfma_f32_16x16x32_bf16(afr[m], bfr[n], acc[m][n], 0, 0, 0);
    __builtin_amdgcn_s_setprio(0);

    // ---- P1: ks=0, mi 4-7 ----
    if (pre) STAGE(t + 1, 1);
#pragma unroll
    for (int m = 0; m < 4; ++m) afr[m] = LDA(bc, 0, 4 + m);
    if (pre) { VMCNT4; } else { VMCNT0; }   // publish this tile's k1 halves
    BARRIER();
    __builtin_amdgcn_s_setprio(1);
#pragma unroll
    for (int m = 0; m < 4; ++m)
#pragma unroll
      for (int n = 0; n < 4; ++n)
        acc[4 + m][n] = __builtin_amdgcn_mfma_f32_16x16x32_bf16(afr[m], bfr[n], acc[4 + m][n], 0, 0, 0);
    __builtin_amdgcn_s_setprio(0);

    // ---- P2: ks=1, mi 0-3 ----
    if (pre) STAGE(t + 1, 2);
#pragma unroll
    for (int n = 0; n < 4; ++n) bfr[n] = LDB(bc, 1, n);
#pragma unroll
    for (int m = 0; m < 4; ++m) afr[m] = LDA(bc, 1, m);
    BARRIER();
    __builtin_amdgcn_s_setprio(1);
#pragma unroll
    for (int m = 0; m < 4; ++m)
#pragma unroll
      for (int n = 0; n < 4; ++n)
        acc[m][n] = __builtin_amdgcn_mfma_f32_16x16x32_bf16(afr[m], bfr[n], acc[m][n], 0, 0, 0);
    __builtin_amdgcn_s_setprio(0);

    // ---- P3: ks=1, mi 4-7 ----
    if (pre) STAGE(t + 1, 3);
#pragma unroll
    for (int m = 0; m < 4; ++m) afr[m] = LDA(bc, 1, 4 + m);
    if (pre) { VMCNT4; } else { VMCNT0; }   // publish next tile's k0 halves
    BARRIER();
    __builtin_amdgcn_s_setprio(1);
#pragma unroll
    for (int m = 0; m < 4; ++m)
#pragma unroll
      for (int n = 0; n < 4; ++n)
        acc[4 + m][n] = __builtin_amdgcn_mfma_f32_16x16x32_bf16(afr[m], bfr[n], acc[4 + m][n], 0, 0, 0);
    __builtin_amdgcn_s_setprio(0);
  }

  // epilogue: D row = kg*4+q (+16*m blocks), col = fr (+16*n)
#pragma unroll
  for (int n = 0; n < 4; ++n) {
    int col = n0 + wc * 64 + n * 16 + fr;
    float bv = bias[col];
#pragma unroll
    for (int m = 0; m < 8; ++m) {
      int row0 = m0 + wr * 128 + m * 16 + kg * 4;
#pragma unroll
      for (int q = 0; q < 4; ++q)
        C[(size_t)(row0 + q) * N + col] = acc[m][n][q] + bv;
    }
  }
}

extern "C" void kernel_launch(void* const* d_in, const int* in_sizes, int n_in,
                              void* d_out, int out_size, void* d_ws, size_t ws_size,
                              hipStream_t stream) {
  const float* x     = (const float*)d_in[0];   // [2,4096,4096]
  const float* oft_r = (const float*)d_in[1];   // [64,64,64]
  const float* W     = (const float*)d_in[2];   // [4096,4096]
  const float* b     = (const float*)d_in[3];   // [4096]
  float* y = (float*)d_out;                     // [8192,4096] f32

  char* ws = (char*)d_ws;
  float* Qxt = (float*)ws;                                 // 1 MiB: Q row-major per block
  bf16*  Wp  = (bf16*)(ws + (1u << 20));                   // 32 MiB: folded W, bf16
  bf16*  xb  = (bf16*)(ws + (1u << 20) + (32u << 20));     // 64 MiB: x, bf16

  cayley_kernel<<<64, 256, 0, stream>>>(oft_r, Qxt);
  dim3 fg(32, 64);
  fold_w_kernel<<<fg, 256, 0, stream>>>(W, Qxt, Wp);
  cast_x_kernel<<<2048, 256, 0, stream>>>(x, xb, 33554432L);
  dim3 gg(4096 / 256, 8192 / 256);   // (16, 32)
  gemm_kernel<<<gg, 512, 0, stream>>>(xb, Wp, b, y, 8192, 4096, 4096);
}